// Round 1
// baseline (1178.793 us; speedup 1.0000x reference)
//
#include <hip/hip_runtime.h>
#include <math.h>

// Problem: coverage attention. B=64, S=2048, H=512.
// e_t[b,s] = v_b + sum_h v_w[h] * tanh( (enc@Wh)[b,s,h] + D[b,h] + cov[b,s]*Wc[h] )
//   with D[b,h] = (dec @ Ws)[b,h] + bs[h] + bh[h] + bc[h]
// a_t = softmax(e_t, axis=s);  out = [a_t | coverage + a_t]
//
// R0: correct fp32 baseline. Fused tiled GEMM (64x64x16, 4x4 micro) with
// tanh+v_w reduction epilogue -> atomicAdd partials into e_t workspace.
// Small kernels for D, zeroing, softmax. MFMA comes next round.

#define B_ 64
#define S_ 2048
#define H_ 512
#define M_ (B_ * S_)

#define BM 64
#define BN 64
#define BK 16
#define LPAD 68  // LDS row stride (floats): keeps float4 alignment, breaks pow2 banks

__global__ __launch_bounds__(256) void zero_kernel(float* __restrict__ p) {
    p[blockIdx.x * 256 + threadIdx.x] = 0.0f;
}

// D[b,h] = dec[b,:] . Ws[:,h] + bs[h] + bh[h] + bc[h]
__global__ __launch_bounds__(512) void dec_kernel(
    const float* __restrict__ dh, const float* __restrict__ Ws,
    const float* __restrict__ bs, const float* __restrict__ bh,
    const float* __restrict__ bc, float* __restrict__ D) {
    const int b = blockIdx.x;
    const int h = threadIdx.x;
    __shared__ float sdh[H_];
    sdh[h] = dh[b * H_ + h];
    __syncthreads();
    float acc = bs[h] + bh[h] + bc[h];
#pragma unroll 8
    for (int k = 0; k < H_; ++k)
        acc = fmaf(sdh[k], Ws[k * H_ + h], acc);
    D[b * H_ + h] = acc;
}

__device__ __forceinline__ float fast_tanh(float x) {
    // 1 - 2/(e^{2x}+1); saturates correctly at +/-inf of __expf
    return 1.0f - 2.0f / (__expf(2.0f * x) + 1.0f);
}

// C-tile = A[row0:row0+64, :] @ Wh[:, n0:n0+64]; epilogue reduces over n (=h)
// with tanh and v_w weights, atomicAdd per-row partials into e_ws.
__global__ __launch_bounds__(256) void gemm_fused(
    const float* __restrict__ A,      // [M_, H_] encoder_output
    const float* __restrict__ Wh,     // [H_, H_] (k-major, [in,out])
    const float* __restrict__ cover,  // [M_]
    const float* __restrict__ Wc,     // [H_]
    const float* __restrict__ vw,     // [H_]
    const float* __restrict__ D,      // [B_, H_]
    float* __restrict__ e_ws) {       // [M_]
    __shared__ float As[BK][LPAD];  // [k][m]
    __shared__ float Bs[BK][LPAD];  // [k][n]

    const int tid = threadIdx.x;
    const int row0 = blockIdx.x * BM;
    const int n0 = blockIdx.y * BN;
    const int b = row0 / S_;  // S_ % BM == 0 -> whole tile in one batch

    const int tx = tid & 15, ty = tid >> 4;
    const int rowA = tid >> 2, kq = (tid & 3) * 4;   // A: 64 rows x 4 float4/row
    const int kB = tid >> 4, nq = (tid & 15) * 4;    // B: 16 k x 16 float4

    float acc[4][4] = {};

    for (int kk = 0; kk < H_; kk += BK) {
        float4 av = *(const float4*)&A[(size_t)(row0 + rowA) * H_ + kk + kq];
        float4 bv = *(const float4*)&Wh[(size_t)(kk + kB) * H_ + n0 + nq];
        As[kq + 0][rowA] = av.x;
        As[kq + 1][rowA] = av.y;
        As[kq + 2][rowA] = av.z;
        As[kq + 3][rowA] = av.w;
        *(float4*)&Bs[kB][nq] = bv;
        __syncthreads();

        float ar[4], br[4];
#pragma unroll
        for (int k = 0; k < BK; ++k) {
            *(float4*)ar = *(const float4*)&As[k][ty * 4];
            *(float4*)br = *(const float4*)&Bs[k][tx * 4];
#pragma unroll
            for (int i = 0; i < 4; ++i)
#pragma unroll
                for (int j = 0; j < 4; ++j)
                    acc[i][j] = fmaf(ar[i], br[j], acc[i][j]);
        }
        __syncthreads();
    }

    // epilogue: x = acc + cov*Wc[h] + D[b,h]; p = sum_j vw*tanh(x); reduce over tx
    const int col0 = n0 + tx * 4;
    float wc[4], dd[4], vv[4];
#pragma unroll
    for (int j = 0; j < 4; ++j) {
        wc[j] = Wc[col0 + j];
        dd[j] = D[b * H_ + col0 + j];
        vv[j] = vw[col0 + j];
    }
#pragma unroll
    for (int i = 0; i < 4; ++i) {
        const int row = row0 + ty * 4 + i;
        const float cv = cover[row];
        float p = 0.0f;
#pragma unroll
        for (int j = 0; j < 4; ++j) {
            float x = acc[i][j] + fmaf(cv, wc[j], dd[j]);
            p = fmaf(vv[j], fast_tanh(x), p);
        }
        // reduce across the 16 lanes sharing this row (tx groups within wave)
        p += __shfl_xor(p, 1, 64);
        p += __shfl_xor(p, 2, 64);
        p += __shfl_xor(p, 4, 64);
        p += __shfl_xor(p, 8, 64);
        if ((tid & 15) == 0) atomicAdd(&e_ws[row], p);
    }
}

__global__ __launch_bounds__(256) void softmax_kernel(
    const float* __restrict__ e_ws, const float* __restrict__ cover,
    const float* __restrict__ vb, float* __restrict__ out) {
    const int b = blockIdx.x;
    const int tid = threadIdx.x;
    const float vbv = vb[0];

    float e[8];
    float mx = -1e30f;
#pragma unroll
    for (int r = 0; r < 8; ++r) {
        e[r] = e_ws[b * S_ + r * 256 + tid] + vbv;
        mx = fmaxf(mx, e[r]);
    }
#pragma unroll
    for (int off = 32; off >= 1; off >>= 1) mx = fmaxf(mx, __shfl_xor(mx, off, 64));

    __shared__ float sm[4], ss[4], sbc[2];
    const int wid = tid >> 6, lane = tid & 63;
    if (lane == 0) sm[wid] = mx;
    __syncthreads();
    if (tid == 0) sbc[0] = fmaxf(fmaxf(sm[0], sm[1]), fmaxf(sm[2], sm[3]));
    __syncthreads();
    mx = sbc[0];

    float ex[8];
    float sum = 0.0f;
#pragma unroll
    for (int r = 0; r < 8; ++r) {
        ex[r] = __expf(e[r] - mx);
        sum += ex[r];
    }
#pragma unroll
    for (int off = 32; off >= 1; off >>= 1) sum += __shfl_xor(sum, off, 64);
    if (lane == 0) ss[wid] = sum;
    __syncthreads();
    if (tid == 0) sbc[1] = ss[0] + ss[1] + ss[2] + ss[3];
    __syncthreads();
    const float inv = 1.0f / sbc[1];

#pragma unroll
    for (int r = 0; r < 8; ++r) {
        const int s = r * 256 + tid;
        const float a = ex[r] * inv;
        out[b * S_ + s] = a;                              // a_t
        out[M_ + b * S_ + s] = cover[b * S_ + s] + a;     // sum_coverage
    }
}

extern "C" void kernel_launch(void* const* d_in, const int* in_sizes, int n_in,
                              void* d_out, int out_size, void* d_ws, size_t ws_size,
                              hipStream_t stream) {
    const float* enc = (const float*)d_in[0];
    const float* dh  = (const float*)d_in[1];
    const float* cov = (const float*)d_in[2];
    const float* Wh  = (const float*)d_in[3];
    const float* bh  = (const float*)d_in[4];
    const float* Ws  = (const float*)d_in[5];
    const float* bs  = (const float*)d_in[6];
    const float* Wc  = (const float*)d_in[7];
    const float* bc  = (const float*)d_in[8];
    const float* vw  = (const float*)d_in[9];
    const float* vb  = (const float*)d_in[10];
    float* out = (float*)d_out;

    float* e_ws = (float*)d_ws;       // [M_]
    float* Dws  = e_ws + M_;          // [B_ * H_]

    zero_kernel<<<M_ / 256, 256, 0, stream>>>(e_ws);
    dec_kernel<<<B_, 512, 0, stream>>>(dh, Ws, bs, bh, bc, Dws);
    dim3 g2(M_ / BM, H_ / BN);
    gemm_fused<<<g2, 256, 0, stream>>>(enc, Wh, cov, Wc, vw, Dws, e_ws);
    softmax_kernel<<<B_, 256, 0, stream>>>(e_ws, cov, vb, out);
}

// Round 2
// 511.145 us; speedup vs baseline: 2.3062x; 2.3062x over previous
//
#include <hip/hip_runtime.h>
#include <math.h>

// Coverage attention. B=64, S=2048, H=512.
// e_t[b,s] = v_b + sum_h v_w[h] * tanh( (enc@Wh)[b,s,h] + D[b,h] + cov[b,s]*Wc[h] )
//   D[b,h] = (dec @ Ws)[b,h] + bs[h] + bh[h] + bc[h]
// out = [softmax(e_t) | coverage + softmax(e_t)]
//
// R1: bf16 MFMA GEMM (16x16x32), BM=64 x BN=256 x BK=32, 4 waves/block.
//  - Wh pre-transposed+cast to bf16 [n][k] so B frags are k-contiguous
//  - B staged via global_load_lds (16B DMA) with add-rotate bank swizzle
//  - A fp32->bf16 converted during staging, LDS rows padded to 56 shorts
//  - epilogue: tanh + v_w reduction in-register, no atomics (2 n-phases)

#define B_ 64
#define S_ 2048
#define H_ 512
#define M_ (B_ * S_)

#define BM 64
#define BN 256
#define BK 32
#define ASTRIDE 56  // shorts per As row: 112B, 16B-aligned, 2-way banks (free)

typedef __attribute__((ext_vector_type(4))) float f32x4;
typedef __attribute__((ext_vector_type(8))) short s16x8;
typedef __attribute__((ext_vector_type(4))) short s16x4;

typedef __attribute__((address_space(1))) void gvoid;
typedef __attribute__((address_space(3))) void lvoid;

__device__ __forceinline__ short f2bf(float f) {
    unsigned u = __float_as_uint(f);
    u += 0x7fffu + ((u >> 16) & 1u);  // RNE
    return (short)(u >> 16);
}

__device__ __forceinline__ float fast_tanh(float x) {
    return 1.0f - 2.0f / (__expf(2.0f * x) + 1.0f);  // saturates correctly
}

// Whbt[n][k] = bf16(Wh[k][n])
__global__ __launch_bounds__(256) void transpose_cast(
    const float* __restrict__ Wh, short* __restrict__ Bt) {
    __shared__ float tile[32][33];
    const int n0 = blockIdx.x * 32, k0 = blockIdx.y * 32;
    const int tx = threadIdx.x & 31, ty = threadIdx.x >> 5;  // 32 x 8
#pragma unroll
    for (int r = 0; r < 32; r += 8)
        tile[ty + r][tx] = Wh[(size_t)(k0 + ty + r) * H_ + n0 + tx];
    __syncthreads();
#pragma unroll
    for (int r = 0; r < 32; r += 8)
        Bt[(size_t)(n0 + ty + r) * H_ + k0 + tx] = f2bf(tile[tx][ty + r]);
}

// D[b,h] = dec[b,:] . Ws[:,h] + bs[h] + bh[h] + bc[h]
__global__ __launch_bounds__(512) void dec_kernel(
    const float* __restrict__ dh, const float* __restrict__ Ws,
    const float* __restrict__ bs, const float* __restrict__ bh,
    const float* __restrict__ bc, float* __restrict__ D) {
    const int b = blockIdx.x;
    const int h = threadIdx.x;
    __shared__ float sdh[H_];
    sdh[h] = dh[b * H_ + h];
    __syncthreads();
    float acc = bs[h] + bh[h] + bc[h];
#pragma unroll 8
    for (int k = 0; k < H_; ++k)
        acc = fmaf(sdh[k], Ws[k * H_ + h], acc);
    D[b * H_ + h] = acc;
}

__global__ __launch_bounds__(256, 3) void gemm_fused(
    const float* __restrict__ A,      // [M_, H_] fp32 encoder
    const short* __restrict__ Bt,     // [H_, H_] bf16, [n][k]
    const float* __restrict__ cover,  // [M_]
    const float* __restrict__ Wc,     // [H_]
    const float* __restrict__ vw,     // [H_]
    const float* __restrict__ D,      // [B_, H_]
    float* __restrict__ e_ws) {       // [2][M_] partials (by n-phase)
    __shared__ short As[BM * ASTRIDE];            // 7168 B
    __shared__ __align__(16) short Bs[BN * BK];   // 16384 B
    __shared__ float sWc[BN], sVw[BN], sD[BN], sCov[BM];
    __shared__ float part[4][BM];

    const int tid = threadIdx.x;
    const int w = tid >> 6;   // wave 0..3
    const int l = tid & 63;
    const int row0 = blockIdx.x * BM;
    const int n0 = blockIdx.y * BN;
    const int b = row0 >> 11;  // /S_

    // stage per-column params + coverage (consumed in epilogue)
    sWc[tid] = Wc[n0 + tid];
    sVw[tid] = vw[n0 + tid];
    sD[tid] = D[b * H_ + n0 + tid];
    if (tid < BM) sCov[tid] = cover[row0 + tid];

    // ---- A staging: thread t loads 8 fp32 (row m = t>>2, k = (t&3)*8 ..+7)
    const int am = tid >> 2;
    const int ak = (tid & 3) * 8;
    const float* aptr = A + (size_t)(row0 + am) * H_ + ak;
    short* adst = &As[am * ASTRIDE + ak];

    // ---- B staging via global_load_lds: wave w, chunks c=0..3
    // LDS flat dest (bytes): (w*4+c)*1024 + l*16  ->  row n_local, swizzled kq
    // n_local = (w*4+c)*16 + (l>>2); swz = l&3; kq = (swz - (n>>1)) & 3
    const int bkq = ((l & 3) - (l >> 3)) & 3;
    const int bn_off = w * 64 + (l >> 2);  // + c*16
    const short* bptr = Bt + (size_t)(n0 + bn_off) * H_ + bkq * 8;

    // ---- fragment read coords
    const int q = l >> 4;    // k-quad / row-quad
    const int ml = l & 15;   // m (A) or n (B) within tile

    f32x4 acc[4][4];
#pragma unroll
    for (int i = 0; i < 4; ++i)
#pragma unroll
        for (int j = 0; j < 4; ++j) acc[i][j] = (f32x4)0.0f;

    float4 av0 = *(const float4*)(aptr);
    float4 av1 = *(const float4*)(aptr + 4);
    aptr += BK;

    for (int kk = 0; kk < H_; kk += BK) {
        // write current A chunk (fp32->bf16)
        s16x4 pk0, pk1;
        pk0.x = f2bf(av0.x); pk0.y = f2bf(av0.y);
        pk0.z = f2bf(av0.z); pk0.w = f2bf(av0.w);
        pk1.x = f2bf(av1.x); pk1.y = f2bf(av1.y);
        pk1.z = f2bf(av1.z); pk1.w = f2bf(av1.w);
        *(s16x4*)(adst) = pk0;
        *(s16x4*)(adst + 4) = pk1;

        // issue B DMA (16B/lane, LDS dest = wave-uniform base + lane*16)
#pragma unroll
        for (int c = 0; c < 4; ++c) {
            __builtin_amdgcn_global_load_lds(
                (gvoid*)(bptr + (size_t)c * 16 * H_),
                (lvoid*)(Bs + (w * 4 + c) * 512),
                16, 0, 0);
        }
        bptr += BK;

        // prefetch next A chunk (drains with the B DMA at the barrier)
        if (kk + BK < H_) {
            av0 = *(const float4*)(aptr);
            av1 = *(const float4*)(aptr + 4);
            aptr += BK;
        }
        __syncthreads();

        s16x8 afr[4], bfr[4];
#pragma unroll
        for (int mi = 0; mi < 4; ++mi)
            afr[mi] = *(const s16x8*)&As[(mi * 16 + ml) * ASTRIDE + q * 8];
#pragma unroll
        for (int ni = 0; ni < 4; ++ni) {
            const int n = w * 64 + ni * 16 + ml;
            bfr[ni] = *(const s16x8*)&Bs[n * BK + (((q + (n >> 1)) & 3) << 3)];
        }
#pragma unroll
        for (int mi = 0; mi < 4; ++mi)
#pragma unroll
            for (int ni = 0; ni < 4; ++ni)
                acc[mi][ni] = __builtin_amdgcn_mfma_f32_16x16x32_bf16(
                    afr[mi], bfr[ni], acc[mi][ni], 0, 0, 0);
        __syncthreads();
    }

    // ---- epilogue: x = acc + cov*Wc + D; p = sum_n vw*tanh(x)
    // C layout: col = ml, row = q*4 + reg (m89-verified)
#pragma unroll
    for (int mi = 0; mi < 4; ++mi) {
        const int rbase = mi * 16 + q * 4;
        const float cv0 = sCov[rbase + 0];
        const float cv1 = sCov[rbase + 1];
        const float cv2 = sCov[rbase + 2];
        const float cv3 = sCov[rbase + 3];
        float p0 = 0.f, p1 = 0.f, p2 = 0.f, p3 = 0.f;
#pragma unroll
        for (int ni = 0; ni < 4; ++ni) {
            const int n = w * 64 + ni * 16 + ml;
            const float wcv = sWc[n], ddv = sD[n], vvv = sVw[n];
            p0 += vvv * fast_tanh(acc[mi][ni].x + fmaf(cv0, wcv, ddv));
            p1 += vvv * fast_tanh(acc[mi][ni].y + fmaf(cv1, wcv, ddv));
            p2 += vvv * fast_tanh(acc[mi][ni].z + fmaf(cv2, wcv, ddv));
            p3 += vvv * fast_tanh(acc[mi][ni].w + fmaf(cv3, wcv, ddv));
        }
#pragma unroll
        for (int s = 1; s < 16; s <<= 1) {
            p0 += __shfl_xor(p0, s, 64);
            p1 += __shfl_xor(p1, s, 64);
            p2 += __shfl_xor(p2, s, 64);
            p3 += __shfl_xor(p3, s, 64);
        }
        if (ml == 0) {
            part[w][rbase + 0] = p0;
            part[w][rbase + 1] = p1;
            part[w][rbase + 2] = p2;
            part[w][rbase + 3] = p3;
        }
    }
    __syncthreads();
    if (tid < BM) {
        float e = part[0][tid] + part[1][tid] + part[2][tid] + part[3][tid];
        e_ws[(size_t)blockIdx.y * M_ + row0 + tid] = e;
    }
}

__global__ __launch_bounds__(256) void softmax_kernel(
    const float* __restrict__ e_ws, const float* __restrict__ cover,
    const float* __restrict__ vb, float* __restrict__ out) {
    const int b = blockIdx.x;
    const int tid = threadIdx.x;
    const float vbv = vb[0];

    float e[8];
    float mx = -1e30f;
#pragma unroll
    for (int r = 0; r < 8; ++r) {
        const int idx = b * S_ + r * 256 + tid;
        e[r] = e_ws[idx] + e_ws[M_ + idx] + vbv;
        mx = fmaxf(mx, e[r]);
    }
#pragma unroll
    for (int off = 32; off >= 1; off >>= 1) mx = fmaxf(mx, __shfl_xor(mx, off, 64));

    __shared__ float sm[4], ss[4], sbc[2];
    const int wid = tid >> 6, lane = tid & 63;
    if (lane == 0) sm[wid] = mx;
    __syncthreads();
    if (tid == 0) sbc[0] = fmaxf(fmaxf(sm[0], sm[1]), fmaxf(sm[2], sm[3]));
    __syncthreads();
    mx = sbc[0];

    float ex[8];
    float sum = 0.0f;
#pragma unroll
    for (int r = 0; r < 8; ++r) {
        ex[r] = __expf(e[r] - mx);
        sum += ex[r];
    }
#pragma unroll
    for (int off = 32; off >= 1; off >>= 1) sum += __shfl_xor(sum, off, 64);
    if (lane == 0) ss[wid] = sum;
    __syncthreads();
    if (tid == 0) sbc[1] = ss[0] + ss[1] + ss[2] + ss[3];
    __syncthreads();
    const float inv = 1.0f / sbc[1];

#pragma unroll
    for (int r = 0; r < 8; ++r) {
        const int s = r * 256 + tid;
        const float a = ex[r] * inv;
        out[b * S_ + s] = a;                           // a_t
        out[M_ + b * S_ + s] = cover[b * S_ + s] + a;  // sum_coverage
    }
}

extern "C" void kernel_launch(void* const* d_in, const int* in_sizes, int n_in,
                              void* d_out, int out_size, void* d_ws, size_t ws_size,
                              hipStream_t stream) {
    const float* enc = (const float*)d_in[0];
    const float* dh  = (const float*)d_in[1];
    const float* cov = (const float*)d_in[2];
    const float* Wh  = (const float*)d_in[3];
    const float* bh  = (const float*)d_in[4];
    const float* Ws  = (const float*)d_in[5];
    const float* bs  = (const float*)d_in[6];
    const float* Wc  = (const float*)d_in[7];
    const float* bc  = (const float*)d_in[8];
    const float* vw  = (const float*)d_in[9];
    const float* vb  = (const float*)d_in[10];
    float* out = (float*)d_out;

    float* e_ws = (float*)d_ws;          // 2 * M_ floats (two n-phases)
    float* Dws  = e_ws + 2 * M_;         // B_*H_ floats
    short* Whbt = (short*)(Dws + B_ * H_);  // H_*H_ bf16

    transpose_cast<<<dim3(H_ / 32, H_ / 32), 256, 0, stream>>>(Wh, Whbt);
    dec_kernel<<<B_, 512, 0, stream>>>(dh, Ws, bs, bh, bc, Dws);
    dim3 g2(M_ / BM, H_ / BN);
    gemm_fused<<<g2, 256, 0, stream>>>(enc, Whbt, cov, Wc, vw, Dws, e_ws);
    softmax_kernel<<<B_, 256, 0, stream>>>(e_ws, cov, vb, out);
}